// Round 8
// baseline (1317.537 us; speedup 1.0000x reference)
//
#include <hip/hip_runtime.h>
#include <hip/hip_bf16.h>
#include <cstdint>

#define N_NODES 50000
#define N_EDGES 800000
#define GENE    256
#define HID     128
#define FEAT    64
#define NCHUNK  98
#define KC      512

typedef __attribute__((ext_vector_type(8))) short bf16x8;
typedef __attribute__((ext_vector_type(4))) float f32x4;
typedef unsigned short u16;
typedef unsigned int u32;

__device__ __forceinline__ u16 f2b(float f) {
  __hip_bfloat16 h = __float2bfloat16(f);
  return *reinterpret_cast<u16*>(&h);
}
__device__ __forceinline__ float b2f(u16 u) {
  return __uint_as_float(((unsigned)u) << 16);
}
__device__ __forceinline__ float b2f_lo(u32 u) { return __uint_as_float(u << 16); }
__device__ __forceinline__ float b2f_hi(u32 u) { return __uint_as_float(u & 0xffff0000u); }

// ---------------- prep: zero deg/cur + build Wt1/Wt2 (bf16 transposed) ----------------

__global__ void k_prep(int* __restrict__ deg, int* __restrict__ cur,
                       const float* __restrict__ W1, u16* __restrict__ Wt1,
                       const float* __restrict__ W2, u16* __restrict__ Wt2) {
  int i = blockIdx.x * 256 + threadIdx.x;
  if (i < N_NODES) { deg[i] = 0; cur[i] = 0; }
  int j = i - N_NODES;
  if (j >= 0 && j < HID * GENE) {
    int n = j / GENE, k = j % GENE;
    Wt1[j] = f2b(W1[(size_t)k * HID + n]);
  }
  int j2 = j - HID * GENE;
  if (j2 >= 0 && j2 < FEAT * HID) {
    int n = j2 / HID, k = j2 % HID;
    Wt2[j2] = f2b(W2[(size_t)k * FEAT + n]);
  }
}

// ---------------- degree / CSR build ----------------

__global__ void k_deg(const int* __restrict__ dst, int* __restrict__ deg) {
  int e4 = blockIdx.x * blockDim.x + threadIdx.x;
  if (e4 * 4 < N_EDGES) {
    int4 d = *(const int4*)(dst + e4 * 4);
    atomicAdd(&deg[d.x], 1);
    atomicAdd(&deg[d.y], 1);
    atomicAdd(&deg[d.z], 1);
    atomicAdd(&deg[d.w], 1);
  }
}

__global__ void k_scan1(const int* __restrict__ deg, int* __restrict__ bsum) {
  __shared__ int s[512];
  int t = threadIdx.x;
  int i = blockIdx.x * 512 + t;
  s[t] = (i < N_NODES) ? deg[i] : 0;
  __syncthreads();
  for (int off = 256; off > 0; off >>= 1) {
    if (t < off) s[t] += s[t + off];
    __syncthreads();
  }
  if (t == 0) bsum[blockIdx.x] = s[0];
}

__global__ void k_scan2(int* bsum, int nb) {
  __shared__ int s[128];
  int t = threadIdx.x;
  int v = (t < nb) ? bsum[t] : 0;
  s[t] = v;
  __syncthreads();
  for (int off = 1; off < 128; off <<= 1) {
    int add = (t >= off) ? s[t - off] : 0;
    __syncthreads();
    s[t] += add;
    __syncthreads();
  }
  if (t < nb) bsum[t] = s[t] - v;  // exclusive
}

__global__ void k_scan3(const int* __restrict__ deg, const int* __restrict__ bsum,
                        int* __restrict__ row_ptr, float* __restrict__ dinv) {
  __shared__ int s[512];
  int t = threadIdx.x;
  int i = blockIdx.x * 512 + t;
  int v = (i < N_NODES) ? deg[i] : 0;
  s[t] = v;
  __syncthreads();
  for (int off = 1; off < 512; off <<= 1) {
    int add = (t >= off) ? s[t - off] : 0;
    __syncthreads();
    s[t] += add;
    __syncthreads();
  }
  int incl = s[t] + bsum[blockIdx.x];
  if (i < N_NODES) {
    row_ptr[i] = incl - v;
    dinv[i] = rsqrtf((float)(v + 1));
  }
  if (i == N_NODES - 1) row_ptr[N_NODES] = incl;
}

__global__ void k_fill(const int* __restrict__ src, const int* __restrict__ dst,
                       const int* __restrict__ row_ptr, int* __restrict__ cursor,
                       int* __restrict__ col) {
  int e4 = blockIdx.x * blockDim.x + threadIdx.x;
  if (e4 * 4 < N_EDGES) {
    int4 d = *(const int4*)(dst + e4 * 4);
    int4 s = *(const int4*)(src + e4 * 4);
    col[row_ptr[d.x] + atomicAdd(&cursor[d.x], 1)] = s.x;
    col[row_ptr[d.y] + atomicAdd(&cursor[d.y], 1)] = s.y;
    col[row_ptr[d.z] + atomicAdd(&cursor[d.z], 1)] = s.z;
    col[row_ptr[d.w] + atomicAdd(&cursor[d.w], 1)] = s.w;
  }
}

// ---- LDS-staged MFMA GEMM: Y[m] = dinv[m]*(X[m] @ W). ----

template<bool F32IN, int NN, int KK>
__global__ __launch_bounds__(256) void gemm_lds(const void* __restrict__ Xv,
                                                const u16* __restrict__ Wt,
                                                const float* __restrict__ dinv,
                                                u16* __restrict__ Y, int reps) {
  constexpr int NF = NN / 32;
  constexpr int KU = KK / 8;
  constexpr int UPT = NN * KK / 8 / 256;
  __shared__ u16 wlds[NN * KK];

  int t = threadIdx.x;
  int w = t >> 6, l = t & 63;
  int lm = l & 15, lg = l >> 4;
  int rowhalf = w >> 1, colhalf = w & 1;
  int m0 = blockIdx.x * 64;
  int cb = colhalf * (NN / 2);

#pragma unroll
  for (int i = 0; i < UPT; ++i) {
    int j = t + i * 256;
    int row = j / KU, u = j - row * KU;
    bf16x8 v = *(const bf16x8*)(Wt + j * 8);
    *(bf16x8*)((char*)wlds + row * (KK * 2) + ((u * 16) ^ ((row & 7) << 4))) = v;
  }
  __syncthreads();

  int ra0 = m0 + rowhalf * 32 + lm;
  int ra1 = ra0 + 16;
  int rs0 = (ra0 < N_NODES) ? ra0 : 0;
  int rs1 = (ra1 < N_NODES) ? ra1 : 0;

  for (int rep = 0; rep < reps; ++rep) {
    asm volatile("" ::: "memory");
    f32x4 acc[2][NF] = {};
#pragma unroll
    for (int k0 = 0; k0 < KK; k0 += 32) {
      bf16x8 a0, a1;
      if constexpr (F32IN) {
        const float* x0 = (const float*)Xv + (size_t)rs0 * KK + k0 + lg * 8;
        const float* x1 = (const float*)Xv + (size_t)rs1 * KK + k0 + lg * 8;
        float4 p0 = *(const float4*)x0, p1 = *(const float4*)(x0 + 4);
        float4 q0 = *(const float4*)x1, q1 = *(const float4*)(x1 + 4);
        a0[0] = (short)f2b(p0.x); a0[1] = (short)f2b(p0.y);
        a0[2] = (short)f2b(p0.z); a0[3] = (short)f2b(p0.w);
        a0[4] = (short)f2b(p1.x); a0[5] = (short)f2b(p1.y);
        a0[6] = (short)f2b(p1.z); a0[7] = (short)f2b(p1.w);
        a1[0] = (short)f2b(q0.x); a1[1] = (short)f2b(q0.y);
        a1[2] = (short)f2b(q0.z); a1[3] = (short)f2b(q0.w);
        a1[4] = (short)f2b(q1.x); a1[5] = (short)f2b(q1.y);
        a1[6] = (short)f2b(q1.z); a1[7] = (short)f2b(q1.w);
      } else {
        a0 = *(const bf16x8*)((const u16*)Xv + (size_t)rs0 * KK + k0 + lg * 8);
        a1 = *(const bf16x8*)((const u16*)Xv + (size_t)rs1 * KK + k0 + lg * 8);
      }
#pragma unroll
      for (int f = 0; f < NF; ++f) {
        int row = cb + f * 16 + lm;
        bf16x8 b = *(const bf16x8*)((char*)wlds + row * (KK * 2) +
                                    (((k0 + lg * 8) * 2) ^ ((row & 7) << 4)));
        acc[0][f] = __builtin_amdgcn_mfma_f32_16x16x32_bf16(a0, b, acc[0][f], 0, 0, 0);
        acc[1][f] = __builtin_amdgcn_mfma_f32_16x16x32_bf16(a1, b, acc[1][f], 0, 0, 0);
      }
    }
#pragma unroll
    for (int rf = 0; rf < 2; ++rf) {
      int mo = m0 + rowhalf * 32 + rf * 16 + lg * 4;
#pragma unroll
      for (int r = 0; r < 4; ++r) {
        int mm = mo + r;
        if (mm < N_NODES) {
          float dv = dinv[mm];
#pragma unroll
          for (int f = 0; f < NF; ++f)
            Y[(size_t)mm * NN + cb + f * 16 + lm] = f2b(acc[rf][f][r] * dv);
        }
      }
    }
  }
}

// ---- agg HID=128: u32 loads, 1 wave/node, 4 nodes/block ----

__global__ __launch_bounds__(256) void k_agg128(
    const u32* __restrict__ Ain, const float* __restrict__ dinv,
    const int* __restrict__ row_ptr, const int* __restrict__ col,
    const float* __restrict__ bias, u32* __restrict__ out, int reps) {
  int t = threadIdx.x;
  int node = blockIdx.x * 4 + (t >> 6);
  int l = t & 63;
  float2 bv = *(const float2*)(bias + 2 * l);

  for (int rep = 0; rep < reps; ++rep) {
    asm volatile("" ::: "memory");
    float di = dinv[node];
    int beg = row_ptr[node], end = row_ptr[node + 1];
    u32 us = Ain[(size_t)node * 64 + l];
    float ax = b2f_lo(us), ay = b2f_hi(us);
    int r = beg;
    for (; r + 4 <= end; r += 4) {
      int s0 = col[r], s1 = col[r + 1], s2 = col[r + 2], s3 = col[r + 3];
      u32 u0 = Ain[(size_t)s0 * 64 + l];
      u32 u1 = Ain[(size_t)s1 * 64 + l];
      u32 u2 = Ain[(size_t)s2 * 64 + l];
      u32 u3 = Ain[(size_t)s3 * 64 + l];
      ax += (b2f_lo(u0) + b2f_lo(u1)) + (b2f_lo(u2) + b2f_lo(u3));
      ay += (b2f_hi(u0) + b2f_hi(u1)) + (b2f_hi(u2) + b2f_hi(u3));
    }
    for (; r < end; ++r) {
      u32 u0 = Ain[(size_t)col[r] * 64 + l];
      ax += b2f_lo(u0); ay += b2f_hi(u0);
    }
    float vx = fmaxf(bv.x + di * ax, 0.f);
    float vy = fmaxf(bv.y + di * ay, 0.f);
    out[(size_t)node * 64 + l] = ((u32)f2b(vy) << 16) | (u32)f2b(vx);
  }
}

// ---- agg FEAT=64: u16 loads, 1 wave/node, 4 nodes/block ----

__global__ __launch_bounds__(256) void k_agg64(
    const u16* __restrict__ Ain, const float* __restrict__ dinv,
    const int* __restrict__ row_ptr, const int* __restrict__ col,
    const float* __restrict__ bias, u16* __restrict__ out, int reps) {
  int t = threadIdx.x;
  int node = blockIdx.x * 4 + (t >> 6);
  int f = t & 63;
  float bf = bias[f];

  for (int rep = 0; rep < reps; ++rep) {
    asm volatile("" ::: "memory");
    float di = dinv[node];
    int beg = row_ptr[node], end = row_ptr[node + 1];
    float acc = b2f(Ain[(size_t)node * 64 + f]);
    int r = beg;
    for (; r + 4 <= end; r += 4) {
      int s0 = col[r], s1 = col[r + 1], s2 = col[r + 2], s3 = col[r + 3];
      float a0 = b2f(Ain[(size_t)s0 * 64 + f]);
      float a1 = b2f(Ain[(size_t)s1 * 64 + f]);
      float a2 = b2f(Ain[(size_t)s2 * 64 + f]);
      float a3 = b2f(Ain[(size_t)s3 * 64 + f]);
      acc += (a0 + a1) + (a2 + a3);
    }
    for (; r < end; ++r) acc += b2f(Ain[(size_t)col[r] * 64 + f]);
    out[(size_t)node * 64 + f] = f2b(bf + di * acc);
  }
}

// ---------------- transpose h2 -> h2t ----------------

__global__ __launch_bounds__(256) void k_tr(const u16* __restrict__ h2,
                                            u16* __restrict__ h2t) {
  __shared__ u16 tile[64][65];
  int i0 = blockIdx.x * 64;
  int t = threadIdx.x;
  int r = t >> 2, c0 = (t & 3) * 16;
  int i = i0 + r;
#pragma unroll
  for (int j = 0; j < 16; ++j)
    tile[r][c0 + j] = (i < N_NODES) ? h2[(size_t)i * 64 + c0 + j] : (u16)0;
  __syncthreads();
  int io = t & 63, n0 = (t >> 6) * 16;
  int i2 = i0 + io;
  if (i2 < N_NODES) {
#pragma unroll
    for (int j = 0; j < 16; ++j)
      h2t[(size_t)(n0 + j) * N_NODES + i2] = tile[io][n0 + j];
  }
}

// ---- final: partial[kc] = data[:, chunk] @ h2[chunk, :] ----

__global__ __launch_bounds__(256) void final_mfma(const float* __restrict__ data,
                                                  const u16* __restrict__ h2t,
                                                  float* __restrict__ partial,
                                                  int reps) {
  int t = threadIdx.x;
  int w = t >> 6, l = t & 63;
  int lm = l & 15, lg = l >> 4;
  int m = blockIdx.x * 64 + w * 16 + lm;
  int k0 = blockIdx.y * KC;
  int kend = k0 + KC; if (kend > N_NODES) kend = N_NODES;
  const float* drow = data + (size_t)m * N_NODES + lg * 8;

  for (int rep = 0; rep < reps; ++rep) {
    asm volatile("" ::: "memory");
    f32x4 acc[4] = {};
    int k = k0;
#pragma unroll 2
    for (; k + 32 <= kend; k += 32) {
      float4 f0 = *(const float4*)(drow + k);
      float4 f1 = *(const float4*)(drow + k + 4);
      bf16x8 a;
      a[0] = (short)f2b(f0.x); a[1] = (short)f2b(f0.y);
      a[2] = (short)f2b(f0.z); a[3] = (short)f2b(f0.w);
      a[4] = (short)f2b(f1.x); a[5] = (short)f2b(f1.y);
      a[6] = (short)f2b(f1.z); a[7] = (short)f2b(f1.w);
#pragma unroll
      for (int f = 0; f < 4; ++f) {
        bf16x8 b = *(const bf16x8*)(h2t + (size_t)(f * 16 + lm) * N_NODES + k + lg * 8);
        acc[f] = __builtin_amdgcn_mfma_f32_16x16x32_bf16(a, b, acc[f], 0, 0, 0);
      }
    }
    if (k < kend) {
      bool ok = (k + lg * 8 + 8) <= kend;
      bf16x8 a = {};
      if (ok) {
        float4 f0 = *(const float4*)(drow + k);
        float4 f1 = *(const float4*)(drow + k + 4);
        a[0] = (short)f2b(f0.x); a[1] = (short)f2b(f0.y);
        a[2] = (short)f2b(f0.z); a[3] = (short)f2b(f0.w);
        a[4] = (short)f2b(f1.x); a[5] = (short)f2b(f1.y);
        a[6] = (short)f2b(f1.z); a[7] = (short)f2b(f1.w);
      }
#pragma unroll
      for (int f = 0; f < 4; ++f) {
        bf16x8 b = {};
        if (ok) b = *(const bf16x8*)(h2t + (size_t)(f * 16 + lm) * N_NODES + k + lg * 8);
        acc[f] = __builtin_amdgcn_mfma_f32_16x16x32_bf16(a, b, acc[f], 0, 0, 0);
      }
    }

    float* pout = partial + (size_t)blockIdx.y * (1024 * FEAT);
    int mo = blockIdx.x * 64 + w * 16 + lg * 4;
#pragma unroll
    for (int f = 0; f < 4; ++f)
#pragma unroll
      for (int r = 0; r < 4; ++r)
        pout[(size_t)(mo + r) * FEAT + f * 16 + lm] = acc[f][r];
  }
}

__global__ __launch_bounds__(256) void k_red(const float* __restrict__ partial,
                                             float* __restrict__ out) {
  int i = blockIdx.x * 256 + threadIdx.x;  // 16384 float4 outputs
  f32x4 s = {};
#pragma unroll
  for (int c = 0; c < NCHUNK; ++c)
    s += *(const f32x4*)(partial + (size_t)c * (1024 * FEAT) + i * 4);
  *(f32x4*)((float*)out + i * 4) = s;
}

// ---------------- launch ----------------

extern "C" void kernel_launch(void* const* d_in, const int* in_sizes, int n_in,
                              void* d_out, int out_size, void* d_ws, size_t ws_size,
                              hipStream_t stream) {
  const float* data = (const float*)d_in[0];
  const float* x    = (const float*)d_in[1];
  const int*   ei   = (const int*)d_in[2];
  const float* W1   = (const float*)d_in[3];
  const float* b1   = (const float*)d_in[4];
  const float* W2   = (const float*)d_in[5];
  const float* b2   = (const float*)d_in[6];
  float* out = (float*)d_out;

  char* ws = (char*)d_ws;
  float* part = (float*)(ws + 0);          // aliases A+Hb (lifetime-disjoint)
  u16*   A    = (u16*)(ws + 0);
  u16*   Hb   = (u16*)(ws + 12800000);
  u16*   h2t  = (u16*)(ws + 25690112);
  u16*   Wt1  = (u16*)(ws + 32090112);
  u16*   Wt2  = (u16*)(ws + 32155648);
  int*   deg  = (int*)(ws + 32172032);
  int*   rowp = (int*)(ws + 32372032);
  int*   cur  = (int*)(ws + 32572048);
  int*   bsum = (int*)(ws + 32772048);
  float* dinv = (float*)(ws + 32772560);
  int*   col  = (int*)(ws + 32972560);

  const int* srcp = ei;
  const int* dstp = ei + N_EDGES;

  // MEASUREMENT ROUND 3: all 5 reppable kernels into top-5 simultaneously.
  // dur/R = per-kernel time; residual vs 312us = CSR + launch overhead.
  const int R_G1 = 12, R_G2 = 40, R_AGG1 = 10, R_AGG2 = 16, R_FIN = 4;

  k_prep<<<(N_NODES + HID * GENE + FEAT * HID + 255) / 256, 256, 0, stream>>>(
      deg, cur, W1, Wt1, W2, Wt2);
  k_deg<<<(N_EDGES / 4 + 255) / 256, 256, 0, stream>>>(dstp, deg);
  int nb = (N_NODES + 511) / 512;  // 98
  k_scan1<<<nb, 512, 0, stream>>>(deg, bsum);
  k_scan2<<<1, 128, 0, stream>>>(bsum, nb);
  k_scan3<<<nb, 512, 0, stream>>>(deg, bsum, rowp, dinv);
  k_fill<<<(N_EDGES / 4 + 255) / 256, 256, 0, stream>>>(srcp, dstp, rowp, cur, col);

  gemm_lds<true, HID, GENE><<<(N_NODES + 63) / 64, 256, 0, stream>>>(x, Wt1, dinv, A, R_G1);
  k_agg128<<<N_NODES / 4, 256, 0, stream>>>((const u32*)A, dinv, rowp, col, b1, (u32*)Hb, R_AGG1);

  gemm_lds<false, FEAT, HID><<<(N_NODES + 63) / 64, 256, 0, stream>>>(Hb, Wt2, dinv, A, R_G2);
  k_agg64<<<N_NODES / 4, 256, 0, stream>>>(A, dinv, rowp, col, b2, Hb, R_AGG2);

  k_tr<<<(N_NODES + 63) / 64, 256, 0, stream>>>(Hb, h2t);

  final_mfma<<<dim3(16, NCHUNK), 256, 0, stream>>>(data, h2t, part, R_FIN);
  k_red<<<(1024 * FEAT) / 4 / 256, 256, 0, stream>>>(part, out);
}

// Round 9
// 273.212 us; speedup vs baseline: 4.8224x; 4.8224x over previous
//
#include <hip/hip_runtime.h>
#include <hip/hip_bf16.h>
#include <cstdint>

#define N_NODES 50000
#define N_EDGES 800000
#define GENE    256
#define HID     128
#define FEAT    64
#define NCHUNK  196
#define KC      256

typedef __attribute__((ext_vector_type(8))) short bf16x8;
typedef __attribute__((ext_vector_type(4))) float f32x4;
typedef unsigned short u16;
typedef unsigned int u32;

__device__ __forceinline__ u16 f2b(float f) {
  __hip_bfloat16 h = __float2bfloat16(f);
  return *reinterpret_cast<u16*>(&h);
}
__device__ __forceinline__ float b2f(u16 u) {
  return __uint_as_float(((unsigned)u) << 16);
}
__device__ __forceinline__ float b2f_lo(u32 u) { return __uint_as_float(u << 16); }
__device__ __forceinline__ float b2f_hi(u32 u) { return __uint_as_float(u & 0xffff0000u); }

__device__ __forceinline__ bf16x8 cvt8(float4 f0, float4 f1) {
  bf16x8 a;
  a[0] = (short)f2b(f0.x); a[1] = (short)f2b(f0.y);
  a[2] = (short)f2b(f0.z); a[3] = (short)f2b(f0.w);
  a[4] = (short)f2b(f1.x); a[5] = (short)f2b(f1.y);
  a[6] = (short)f2b(f1.z); a[7] = (short)f2b(f1.w);
  return a;
}

// ---------------- prep: zero deg/cur + build Wt1/Wt2 (bf16 transposed) ----------------

__global__ void k_prep(int* __restrict__ deg, int* __restrict__ cur,
                       const float* __restrict__ W1, u16* __restrict__ Wt1,
                       const float* __restrict__ W2, u16* __restrict__ Wt2) {
  int i = blockIdx.x * 256 + threadIdx.x;
  if (i < N_NODES) { deg[i] = 0; cur[i] = 0; }
  int j = i - N_NODES;
  if (j >= 0 && j < HID * GENE) {
    int n = j / GENE, k = j % GENE;
    Wt1[j] = f2b(W1[(size_t)k * HID + n]);
  }
  int j2 = j - HID * GENE;
  if (j2 >= 0 && j2 < FEAT * HID) {
    int n = j2 / HID, k = j2 % HID;
    Wt2[j2] = f2b(W2[(size_t)k * FEAT + n]);
  }
}

// ---------------- degree / CSR build ----------------

__global__ void k_deg(const int* __restrict__ dst, int* __restrict__ deg) {
  int e4 = blockIdx.x * blockDim.x + threadIdx.x;
  if (e4 * 4 < N_EDGES) {
    int4 d = *(const int4*)(dst + e4 * 4);
    atomicAdd(&deg[d.x], 1);
    atomicAdd(&deg[d.y], 1);
    atomicAdd(&deg[d.z], 1);
    atomicAdd(&deg[d.w], 1);
  }
}

__global__ void k_scan1(const int* __restrict__ deg, int* __restrict__ bsum) {
  __shared__ int s[512];
  int t = threadIdx.x;
  int i = blockIdx.x * 512 + t;
  s[t] = (i < N_NODES) ? deg[i] : 0;
  __syncthreads();
  for (int off = 256; off > 0; off >>= 1) {
    if (t < off) s[t] += s[t + off];
    __syncthreads();
  }
  if (t == 0) bsum[blockIdx.x] = s[0];
}

__global__ void k_scan2(int* bsum, int nb) {
  __shared__ int s[128];
  int t = threadIdx.x;
  int v = (t < nb) ? bsum[t] : 0;
  s[t] = v;
  __syncthreads();
  for (int off = 1; off < 128; off <<= 1) {
    int add = (t >= off) ? s[t - off] : 0;
    __syncthreads();
    s[t] += add;
    __syncthreads();
  }
  if (t < nb) bsum[t] = s[t] - v;  // exclusive
}

__global__ void k_scan3(const int* __restrict__ deg, const int* __restrict__ bsum,
                        int* __restrict__ row_ptr, float* __restrict__ dinv) {
  __shared__ int s[512];
  int t = threadIdx.x;
  int i = blockIdx.x * 512 + t;
  int v = (i < N_NODES) ? deg[i] : 0;
  s[t] = v;
  __syncthreads();
  for (int off = 1; off < 512; off <<= 1) {
    int add = (t >= off) ? s[t - off] : 0;
    __syncthreads();
    s[t] += add;
    __syncthreads();
  }
  int incl = s[t] + bsum[blockIdx.x];
  if (i < N_NODES) {
    row_ptr[i] = incl - v;
    dinv[i] = rsqrtf((float)(v + 1));
  }
  if (i == N_NODES - 1) row_ptr[N_NODES] = incl;
}

__global__ void k_fill(const int* __restrict__ src, const int* __restrict__ dst,
                       const int* __restrict__ row_ptr, int* __restrict__ cursor,
                       int* __restrict__ col) {
  int e4 = blockIdx.x * blockDim.x + threadIdx.x;
  if (e4 * 4 < N_EDGES) {
    int4 d = *(const int4*)(dst + e4 * 4);
    int4 s = *(const int4*)(src + e4 * 4);
    col[row_ptr[d.x] + atomicAdd(&cursor[d.x], 1)] = s.x;
    col[row_ptr[d.y] + atomicAdd(&cursor[d.y], 1)] = s.y;
    col[row_ptr[d.z] + atomicAdd(&cursor[d.z], 1)] = s.z;
    col[row_ptr[d.w] + atomicAdd(&cursor[d.w], 1)] = s.w;
  }
}

// ---- LDS-staged MFMA GEMM: Y[m] = dinv[m]*(X[m] @ W). ----

template<bool F32IN, int NN, int KK>
__global__ __launch_bounds__(256) void gemm_lds(const void* __restrict__ Xv,
                                                const u16* __restrict__ Wt,
                                                const float* __restrict__ dinv,
                                                u16* __restrict__ Y) {
  constexpr int NF = NN / 32;
  constexpr int KU = KK / 8;
  constexpr int UPT = NN * KK / 8 / 256;
  __shared__ u16 wlds[NN * KK];

  int t = threadIdx.x;
  int w = t >> 6, l = t & 63;
  int lm = l & 15, lg = l >> 4;
  int rowhalf = w >> 1, colhalf = w & 1;
  int m0 = blockIdx.x * 64;
  int cb = colhalf * (NN / 2);

#pragma unroll
  for (int i = 0; i < UPT; ++i) {
    int j = t + i * 256;
    int row = j / KU, u = j - row * KU;
    bf16x8 v = *(const bf16x8*)(Wt + j * 8);
    *(bf16x8*)((char*)wlds + row * (KK * 2) + ((u * 16) ^ ((row & 7) << 4))) = v;
  }
  __syncthreads();

  int ra0 = m0 + rowhalf * 32 + lm;
  int ra1 = ra0 + 16;
  int rs0 = (ra0 < N_NODES) ? ra0 : 0;
  int rs1 = (ra1 < N_NODES) ? ra1 : 0;

  f32x4 acc[2][NF] = {};
#pragma unroll
  for (int k0 = 0; k0 < KK; k0 += 32) {
    bf16x8 a0, a1;
    if constexpr (F32IN) {
      const float* x0 = (const float*)Xv + (size_t)rs0 * KK + k0 + lg * 8;
      const float* x1 = (const float*)Xv + (size_t)rs1 * KK + k0 + lg * 8;
      a0 = cvt8(*(const float4*)x0, *(const float4*)(x0 + 4));
      a1 = cvt8(*(const float4*)x1, *(const float4*)(x1 + 4));
    } else {
      a0 = *(const bf16x8*)((const u16*)Xv + (size_t)rs0 * KK + k0 + lg * 8);
      a1 = *(const bf16x8*)((const u16*)Xv + (size_t)rs1 * KK + k0 + lg * 8);
    }
#pragma unroll
    for (int f = 0; f < NF; ++f) {
      int row = cb + f * 16 + lm;
      bf16x8 b = *(const bf16x8*)((char*)wlds + row * (KK * 2) +
                                  (((k0 + lg * 8) * 2) ^ ((row & 7) << 4)));
      acc[0][f] = __builtin_amdgcn_mfma_f32_16x16x32_bf16(a0, b, acc[0][f], 0, 0, 0);
      acc[1][f] = __builtin_amdgcn_mfma_f32_16x16x32_bf16(a1, b, acc[1][f], 0, 0, 0);
    }
  }
#pragma unroll
  for (int rf = 0; rf < 2; ++rf) {
    int mo = m0 + rowhalf * 32 + rf * 16 + lg * 4;
#pragma unroll
    for (int r = 0; r < 4; ++r) {
      int mm = mo + r;
      if (mm < N_NODES) {
        float dv = dinv[mm];
#pragma unroll
        for (int f = 0; f < NF; ++f)
          Y[(size_t)mm * NN + cb + f * 16 + lm] = f2b(acc[rf][f][r] * dv);
      }
    }
  }
}

// ---- agg HID=128: u32 loads, 1 wave/node, 4 nodes/block ----

__global__ __launch_bounds__(256) void k_agg128(
    const u32* __restrict__ Ain, const float* __restrict__ dinv,
    const int* __restrict__ row_ptr, const int* __restrict__ col,
    const float* __restrict__ bias, u32* __restrict__ out) {
  int t = threadIdx.x;
  int node = blockIdx.x * 4 + (t >> 6);
  int l = t & 63;
  float2 bv = *(const float2*)(bias + 2 * l);

  float di = dinv[node];
  int beg = row_ptr[node], end = row_ptr[node + 1];
  u32 us = Ain[(size_t)node * 64 + l];
  float ax = b2f_lo(us), ay = b2f_hi(us);
  int r = beg;
  for (; r + 4 <= end; r += 4) {
    int s0 = col[r], s1 = col[r + 1], s2 = col[r + 2], s3 = col[r + 3];
    u32 u0 = Ain[(size_t)s0 * 64 + l];
    u32 u1 = Ain[(size_t)s1 * 64 + l];
    u32 u2 = Ain[(size_t)s2 * 64 + l];
    u32 u3 = Ain[(size_t)s3 * 64 + l];
    ax += (b2f_lo(u0) + b2f_lo(u1)) + (b2f_lo(u2) + b2f_lo(u3));
    ay += (b2f_hi(u0) + b2f_hi(u1)) + (b2f_hi(u2) + b2f_hi(u3));
  }
  for (; r < end; ++r) {
    u32 u0 = Ain[(size_t)col[r] * 64 + l];
    ax += b2f_lo(u0); ay += b2f_hi(u0);
  }
  float vx = fmaxf(bv.x + di * ax, 0.f);
  float vy = fmaxf(bv.y + di * ay, 0.f);
  out[(size_t)node * 64 + l] = ((u32)f2b(vy) << 16) | (u32)f2b(vx);
}

// ---- agg FEAT=64: u16 loads, 1 wave/node, 4 nodes/block ----

__global__ __launch_bounds__(256) void k_agg64(
    const u16* __restrict__ Ain, const float* __restrict__ dinv,
    const int* __restrict__ row_ptr, const int* __restrict__ col,
    const float* __restrict__ bias, u16* __restrict__ out) {
  int t = threadIdx.x;
  int node = blockIdx.x * 4 + (t >> 6);
  int f = t & 63;
  float bf = bias[f];

  float di = dinv[node];
  int beg = row_ptr[node], end = row_ptr[node + 1];
  float acc = b2f(Ain[(size_t)node * 64 + f]);
  int r = beg;
  for (; r + 4 <= end; r += 4) {
    int s0 = col[r], s1 = col[r + 1], s2 = col[r + 2], s3 = col[r + 3];
    float a0 = b2f(Ain[(size_t)s0 * 64 + f]);
    float a1 = b2f(Ain[(size_t)s1 * 64 + f]);
    float a2 = b2f(Ain[(size_t)s2 * 64 + f]);
    float a3 = b2f(Ain[(size_t)s3 * 64 + f]);
    acc += (a0 + a1) + (a2 + a3);
  }
  for (; r < end; ++r) acc += b2f(Ain[(size_t)col[r] * 64 + f]);
  out[(size_t)node * 64 + f] = f2b(bf + di * acc);
}

// ---------------- transpose h2 -> h2t ----------------

__global__ __launch_bounds__(256) void k_tr(const u16* __restrict__ h2,
                                            u16* __restrict__ h2t) {
  __shared__ u16 tile[64][65];
  int i0 = blockIdx.x * 64;
  int t = threadIdx.x;
  int r = t >> 2, c0 = (t & 3) * 16;
  int i = i0 + r;
#pragma unroll
  for (int j = 0; j < 16; ++j)
    tile[r][c0 + j] = (i < N_NODES) ? h2[(size_t)i * 64 + c0 + j] : (u16)0;
  __syncthreads();
  int io = t & 63, n0 = (t >> 6) * 16;
  int i2 = i0 + io;
  if (i2 < N_NODES) {
#pragma unroll
    for (int j = 0; j < 16; ++j)
      h2t[(size_t)(n0 + j) * N_NODES + i2] = tile[io][n0 + j];
  }
}

// ---- final v2: B-chunk staged in LDS (32KB, XOR-swizzled, zero-padded);
//      A streamed with unroll-4 (8 independent loads in flight). ----

__global__ __launch_bounds__(256) void final_mfma(const float* __restrict__ data,
                                                  const u16* __restrict__ h2t,
                                                  float* __restrict__ partial) {
  constexpr int KU = KC / 8;  // 16B units per LDS row
  __shared__ u16 blds[64 * KC];  // 32 KB

  int t = threadIdx.x;
  int w = t >> 6, l = t & 63;
  int lm = l & 15, lg = l >> 4;
  int kc0 = blockIdx.y * KC;
  int klen = N_NODES - kc0; if (klen > KC) klen = KC;

  // stage h2t[0:64][kc0:kc0+KC] -> LDS, swizzled, zero-padded past N_NODES
#pragma unroll
  for (int i = 0; i < 64 * KU / 256; ++i) {
    int j = t + i * 256;
    int row = j / KU, u = j - row * KU;
    int kpos = kc0 + u * 8;
    bf16x8 v = {};
    if (kpos + 8 <= N_NODES) v = *(const bf16x8*)(h2t + (size_t)row * N_NODES + kpos);
    *(bf16x8*)((char*)blds + row * (KC * 2) + ((u * 16) ^ ((row & 7) << 4))) = v;
  }
  __syncthreads();

  int m = blockIdx.x * 64 + w * 16 + lm;
  const float* drow = data + (size_t)m * N_NODES + kc0 + lg * 8;
  f32x4 acc[4] = {};

  auto bload = [&](int koff, int f) -> bf16x8 {
    int row = f * 16 + lm;
    return *(const bf16x8*)((char*)blds + row * (KC * 2) +
                            ((koff * 2) ^ ((row & 7) << 4)));
  };

  int kk = 0;
  for (; kk + 128 <= klen; kk += 128) {          // unroll-4: 8 loads in flight
    float4 fa[4][2];
#pragma unroll
    for (int s = 0; s < 4; ++s) {
      fa[s][0] = *(const float4*)(drow + kk + s * 32);
      fa[s][1] = *(const float4*)(drow + kk + s * 32 + 4);
    }
#pragma unroll
    for (int s = 0; s < 4; ++s) {
      bf16x8 a = cvt8(fa[s][0], fa[s][1]);
#pragma unroll
      for (int f = 0; f < 4; ++f)
        acc[f] = __builtin_amdgcn_mfma_f32_16x16x32_bf16(a, bload(kk + s * 32 + lg * 8, f), acc[f], 0, 0, 0);
    }
  }
  for (; kk + 32 <= klen; kk += 32) {
    bf16x8 a = cvt8(*(const float4*)(drow + kk), *(const float4*)(drow + kk + 4));
#pragma unroll
    for (int f = 0; f < 4; ++f)
      acc[f] = __builtin_amdgcn_mfma_f32_16x16x32_bf16(a, bload(kk + lg * 8, f), acc[f], 0, 0, 0);
  }
  if (kk < klen) {  // 16-wide K tail (last chunk only); LDS is zero-padded
    bool ok = (kk + lg * 8 + 8) <= klen;
    bf16x8 a = {};
    if (ok) a = cvt8(*(const float4*)(drow + kk), *(const float4*)(drow + kk + 4));
#pragma unroll
    for (int f = 0; f < 4; ++f)
      acc[f] = __builtin_amdgcn_mfma_f32_16x16x32_bf16(a, bload(kk + lg * 8, f), acc[f], 0, 0, 0);
  }

  float* pout = partial + (size_t)blockIdx.y * (1024 * FEAT);
  int mo = blockIdx.x * 64 + w * 16 + lg * 4;
#pragma unroll
  for (int f = 0; f < 4; ++f)
#pragma unroll
    for (int r = 0; r < 4; ++r)
      pout[(size_t)(mo + r) * FEAT + f * 16 + lm] = acc[f][r];
}

__global__ __launch_bounds__(256) void k_red(const float* __restrict__ partial,
                                             float* __restrict__ out) {
  int i = blockIdx.x * 256 + threadIdx.x;  // 16384 float4 outputs
  f32x4 s = {};
#pragma unroll
  for (int c = 0; c < NCHUNK; ++c)
    s += *(const f32x4*)(partial + (size_t)c * (1024 * FEAT) + i * 4);
  *(f32x4*)((float*)out + i * 4) = s;
}

// ---------------- launch ----------------

extern "C" void kernel_launch(void* const* d_in, const int* in_sizes, int n_in,
                              void* d_out, int out_size, void* d_ws, size_t ws_size,
                              hipStream_t stream) {
  const float* data = (const float*)d_in[0];
  const float* x    = (const float*)d_in[1];
  const int*   ei   = (const int*)d_in[2];
  const float* W1   = (const float*)d_in[3];
  const float* b1   = (const float*)d_in[4];
  const float* W2   = (const float*)d_in[5];
  const float* b2   = (const float*)d_in[6];
  float* out = (float*)d_out;

  char* ws = (char*)d_ws;
  u16*   A    = (u16*)(ws + 0);            // 12.8 MB
  u16*   Hb   = (u16*)(ws + 12800000);     // 12.8 MB
  u16*   h2t  = (u16*)(ws + 25690112);     // 6.4 MB
  u16*   Wt1  = (u16*)(ws + 32090112);
  u16*   Wt2  = (u16*)(ws + 32155648);
  int*   deg  = (int*)(ws + 32172032);
  int*   rowp = (int*)(ws + 32372032);
  int*   cur  = (int*)(ws + 32572048);
  int*   bsum = (int*)(ws + 32772048);
  float* dinv = (float*)(ws + 32772560);
  int*   col  = (int*)(ws + 32972560);     // 3.2 MB
  float* part = (float*)(ws + 36200448);   // 196x1024x64 f32 = 51.4 MB

  const int* srcp = ei;
  const int* dstp = ei + N_EDGES;

  k_prep<<<(N_NODES + HID * GENE + FEAT * HID + 255) / 256, 256, 0, stream>>>(
      deg, cur, W1, Wt1, W2, Wt2);
  k_deg<<<(N_EDGES / 4 + 255) / 256, 256, 0, stream>>>(dstp, deg);
  int nb = (N_NODES + 511) / 512;  // 98
  k_scan1<<<nb, 512, 0, stream>>>(deg, bsum);
  k_scan2<<<1, 128, 0, stream>>>(bsum, nb);
  k_scan3<<<nb, 512, 0, stream>>>(deg, bsum, rowp, dinv);
  k_fill<<<(N_EDGES / 4 + 255) / 256, 256, 0, stream>>>(srcp, dstp, rowp, cur, col);

  gemm_lds<true, HID, GENE><<<(N_NODES + 63) / 64, 256, 0, stream>>>(x, Wt1, dinv, A);
  k_agg128<<<N_NODES / 4, 256, 0, stream>>>((const u32*)A, dinv, rowp, col, b1, (u32*)Hb);

  gemm_lds<false, FEAT, HID><<<(N_NODES + 63) / 64, 256, 0, stream>>>(Hb, Wt2, dinv, A);
  k_agg64<<<N_NODES / 4, 256, 0, stream>>>(A, dinv, rowp, col, b2, Hb);

  k_tr<<<(N_NODES + 63) / 64, 256, 0, stream>>>(Hb, h2t);

  final_mfma<<<dim3(16, NCHUNK), 256, 0, stream>>>(data, h2t, part);
  k_red<<<(1024 * FEAT) / 4 / 256, 256, 0, stream>>>(part, out);
}